// Round 2
// baseline (396.754 us; speedup 1.0000x reference)
//
#include <hip/hip_runtime.h>
#include <hip/hip_bf16.h>

// ROUND 18. r17 = 375.8 us. Counters: gemm1_scatter = 100 us top dispatch,
// MfmaUtil 1.2%, VALUBusy 3%, HBM 12% -> latency/transaction-bound.
// WRITE_SIZE 85 MB = 35 MB useful + ~51 MB (= 800K x 64B line-granular
// scatter transactions). Scatter half is 1 edge/thread: one atomic then one
// DEPENDENT random 4B store -> no MLP. Change (scatter branch only):
//   - 4 edges/thread (batched independent atomics, then batched stores)
//   - nt loads for ei, nt stores for csr_src (once-touched streams)
// Predict: gemm1_scatter 100 -> ~75 us, total -> ~350. If unchanged, the
// gemm write path dominates -> unfuse next round to measure the split.

#define N_NODES 50000
#define N_EDGES 800000
#define NB_SCAN 196   // ceil(50000/256)
#define NPAD    50048 // 782*64
#define GEMM_BLKS 782
#define SCAT_BLKS 782 // ceil(800000/1024), 4 edges/thread

using bf16 = __hip_bfloat16;
typedef __attribute__((ext_vector_type(8))) short bf16x8;
typedef __attribute__((ext_vector_type(4))) float f32x4;

__device__ __forceinline__ float b2f(unsigned short u) {
    unsigned int x = ((unsigned int)u) << 16;
    return __builtin_bit_cast(float, x);
}

struct WPtrs { const float* p[8]; };

// ---------------- fused prep: conv_x / conv_w / hist ----------------
__global__ __launch_bounds__(256) void prep(const float* __restrict__ x,
                                            bf16* __restrict__ xb,
                                            WPtrs wp, bf16* __restrict__ wb,
                                            const int* __restrict__ ei,
                                            int* __restrict__ deg) {
    const int gs = gridDim.x * 256;
    const int t0 = blockIdx.x * 256 + threadIdx.x;
    if (blockIdx.y == 0) {
        for (int i = t0; i < N_NODES * 128; i += gs)
            xb[i] = __float2bfloat16(x[i]);
    } else if (blockIdx.y == 1) {
        for (int i = t0; i < 49152; i += gs) {
            int y, o;
            if (i < 32768) { y = i >> 13; o = i & 8191; }
            else { y = 4 + ((i - 32768) >> 12); o = (i - 32768) & 4095; }
            wb[i] = __float2bfloat16(wp.p[y][o]);
        }
    } else {
        for (int e = t0; e < N_EDGES; e += gs)
            atomicAdd(&deg[ei[N_EDGES + e]], 1);
    }
}

// ---------------- MFMA GEMM body (64-row tile, 4 weight mats) ----------------
template <int K>
__device__ __forceinline__ void gemm_body(
    int blk, int tid,
    const bf16* __restrict__ A, const bf16* __restrict__ wb,
    const float* __restrict__ bq, const float* __restrict__ bk,
    const float* __restrict__ bv, const float* __restrict__ bs,
    bf16* __restrict__ qb, bf16* __restrict__ kvb, float* __restrict__ s) {
    const int wave = tid >> 6;
    const int lane = tid & 63;
    const int row0 = blk * 64;
    const int m  = lane & 15;
    const int kg = lane >> 4;
    const bf16* W = wb + (size_t)wave * 64 * K;

    f32x4 acc[4][4];
#pragma unroll
    for (int i = 0; i < 4; ++i)
#pragma unroll
        for (int j = 0; j < 4; ++j) acc[i][j] = (f32x4){0.f, 0.f, 0.f, 0.f};

#pragma unroll
    for (int k0 = 0; k0 < K; k0 += 32) {
        bf16x8 a[4], b[4];
#pragma unroll
        for (int i = 0; i < 4; ++i)
            a[i] = *(const bf16x8*)(A + (size_t)(row0 + i * 16 + m) * K + k0 + kg * 8);
#pragma unroll
        for (int j = 0; j < 4; ++j)
            b[j] = *(const bf16x8*)(W + (size_t)(j * 16 + m) * K + k0 + kg * 8);
#pragma unroll
        for (int i = 0; i < 4; ++i)
#pragma unroll
            for (int j = 0; j < 4; ++j)
                acc[i][j] = __builtin_amdgcn_mfma_f32_16x16x32_bf16(a[i], b[j], acc[i][j], 0, 0, 0);
    }

    const int crow = (lane >> 4) * 4;
    const int ccol = lane & 15;
    const float* B = (wave == 0) ? bq : (wave == 1) ? bk : (wave == 2) ? bv : bs;
    float bias[4];
#pragma unroll
    for (int j = 0; j < 4; ++j) bias[j] = B[j * 16 + ccol];

#pragma unroll
    for (int i = 0; i < 4; ++i)
#pragma unroll
        for (int r = 0; r < 4; ++r) {
            int gr = row0 + i * 16 + crow + r;
            if (gr >= N_NODES) continue;
#pragma unroll
            for (int j = 0; j < 4; ++j) {
                float val = acc[i][j][r] + bias[j];
                size_t idx = (size_t)gr * 64 + j * 16 + ccol;
                if (wave == 0) qb[idx] = __float2bfloat16(val);
                else if (wave == 1) kvb[idx * 2] = __float2bfloat16(val);
                else if (wave == 2) kvb[idx * 2 + 1] = __float2bfloat16(val);
                else s[idx] = val;
            }
        }
}

// layer-1 GEMM + scatter fused (independent work in one dispatch)
// scatter: 4 edges/thread -> 4 independent atomics in flight, then 4
// independent nt stores (was 1 edge/thread, dependent chain, no MLP).
__global__ __launch_bounds__(256) void gemm1_scatter(
    const bf16* __restrict__ A, const bf16* __restrict__ wb,
    const float* __restrict__ bq, const float* __restrict__ bk,
    const float* __restrict__ bv, const float* __restrict__ bs,
    bf16* __restrict__ qb, bf16* __restrict__ kvb, float* __restrict__ s,
    const int* __restrict__ ei, int* __restrict__ cursor,
    int* __restrict__ csr_src) {
    if (blockIdx.x < GEMM_BLKS) {
        gemm_body<128>(blockIdx.x, threadIdx.x, A, wb, bq, bk, bv, bs, qb, kvb, s);
    } else {
        const int base = (blockIdx.x - GEMM_BLKS) * 1024 + threadIdx.x;
        int dst[4], src[4];
#pragma unroll
        for (int u = 0; u < 4; ++u) {
            const int e = base + u * 256;
            if (e < N_EDGES) {
                dst[u] = __builtin_nontemporal_load(ei + N_EDGES + e);
                src[u] = __builtin_nontemporal_load(ei + e);
            } else {
                dst[u] = -1;
            }
        }
        int pos[4];
#pragma unroll
        for (int u = 0; u < 4; ++u)
            if (dst[u] >= 0) pos[u] = atomicAdd(&cursor[dst[u]], 1);
#pragma unroll
        for (int u = 0; u < 4; ++u)
            if (dst[u] >= 0) __builtin_nontemporal_store(src[u], csr_src + pos[u]);
    }
}

__global__ __launch_bounds__(256) void gemm2(
    const bf16* __restrict__ A, const bf16* __restrict__ wb,
    const float* __restrict__ bq, const float* __restrict__ bk,
    const float* __restrict__ bv, const float* __restrict__ bs,
    bf16* __restrict__ qb, bf16* __restrict__ kvb, float* __restrict__ s) {
    gemm_body<64>(blockIdx.x, threadIdx.x, A, wb, bq, bk, bv, bs, qb, kvb, s);
}

// ---------------- CSR scan ----------------
__global__ __launch_bounds__(256) void scan1(const int* __restrict__ deg,
                                             int* __restrict__ off,
                                             int* __restrict__ bsum) {
    __shared__ int sm[256];
    int i = blockIdx.x * 256 + threadIdx.x;
    int v = (i < N_NODES) ? deg[i] : 0;
    sm[threadIdx.x] = v;
    __syncthreads();
    for (int st = 1; st < 256; st <<= 1) {
        int t = (threadIdx.x >= (unsigned)st) ? sm[threadIdx.x - st] : 0;
        __syncthreads();
        sm[threadIdx.x] += t;
        __syncthreads();
    }
    if (i < N_NODES) off[i] = sm[threadIdx.x] - v;
    if (threadIdx.x == 255) bsum[blockIdx.x] = sm[255];
}

__global__ __launch_bounds__(256) void scan2(const int* __restrict__ bsum,
                                             int* __restrict__ boff) {
    __shared__ int sm[256];
    int b = threadIdx.x;
    int v = (b < NB_SCAN) ? bsum[b] : 0;
    sm[b] = v;
    __syncthreads();
    for (int st = 1; st < 256; st <<= 1) {
        int t = (b >= st) ? sm[b - st] : 0;
        __syncthreads();
        sm[b] += t;
        __syncthreads();
    }
    if (b < NB_SCAN) boff[b] = sm[b] - v;
    if (b == 255) boff[NB_SCAN] = sm[255];
}

__global__ __launch_bounds__(256) void scan3(int* __restrict__ off,
                                             const int* __restrict__ boff,
                                             int* __restrict__ cursor) {
    int i = blockIdx.x * 256 + threadIdx.x;
    if (i < N_NODES) {
        int v = off[i] + boff[blockIdx.x];
        off[i] = v;
        cursor[i] = v;
    }
    if (i == 0) off[N_NODES] = boff[NB_SCAN];
}

// ------------- Aggregation: wave/node, nt streaming, unroll 16 -------------
template <int H, bool RELU, typename OT>  // D = 64/H
__global__ __launch_bounds__(256) void agg_csr(const int* __restrict__ off,
                                               const int* __restrict__ csr_src,
                                               const bf16* __restrict__ qb,
                                               const unsigned int* __restrict__ kvu,
                                               const float* __restrict__ s,
                                               OT* __restrict__ out) {
    const int D = 64 / H;
    const float scale = (D == 16) ? 0.25f : 0.125f;
    const int lane = threadIdx.x & 63;
    const int n = (blockIdx.x * 256 + threadIdx.x) >> 6;
    if (n >= N_NODES) return;

    // q read once -> non-temporal (don't evict kv rows from L2)
    const float qv = b2f(__builtin_nontemporal_load(
        (const unsigned short*)qb + (size_t)n * 64 + lane));
    float acc = 0.f, dsum = 0.f;
    int j = off[n];
    const int j1 = off[n + 1];

    for (; j + 15 < j1; j += 16) {
        unsigned int w[16];
#pragma unroll
        for (int u = 0; u < 16; ++u)
            w[u] = kvu[(size_t)csr_src[j + u] * 64 + lane];
        float p[16];
#pragma unroll
        for (int u = 0; u < 16; ++u) p[u] = qv * b2f((unsigned short)w[u]);
#pragma unroll
        for (int o = 1; o < D; o <<= 1)
#pragma unroll
            for (int u = 0; u < 16; ++u) p[u] += __shfl_xor(p[u], o, 64);
#pragma unroll
        for (int u = 0; u < 16; ++u) {
            float e = __expf(p[u] * scale);
            acc += e * b2f((unsigned short)(w[u] >> 16));
            dsum += e;
        }
    }
    for (; j + 3 < j1; j += 4) {
        unsigned int w[4];
#pragma unroll
        for (int u = 0; u < 4; ++u)
            w[u] = kvu[(size_t)csr_src[j + u] * 64 + lane];
        float p[4];
#pragma unroll
        for (int u = 0; u < 4; ++u) p[u] = qv * b2f((unsigned short)w[u]);
#pragma unroll
        for (int o = 1; o < D; o <<= 1)
#pragma unroll
            for (int u = 0; u < 4; ++u) p[u] += __shfl_xor(p[u], o, 64);
#pragma unroll
        for (int u = 0; u < 4; ++u) {
            float e = __expf(p[u] * scale);
            acc += e * b2f((unsigned short)(w[u] >> 16));
            dsum += e;
        }
    }
    for (; j < j1; ++j) {
        unsigned int w = kvu[(size_t)csr_src[j] * 64 + lane];
        float p = qv * b2f((unsigned short)w);
#pragma unroll
        for (int o = 1; o < D; o <<= 1) p += __shfl_xor(p, o, 64);
        float e = __expf(p * scale);
        acc += e * b2f((unsigned short)(w >> 16));
        dsum += e;
    }
    float a = (dsum != 0.f) ? acc / dsum : 0.f;
    float sk = __builtin_nontemporal_load(s + (size_t)n * 64 + lane);
    float val = a + sk;
    if (RELU) val = fmaxf(val, 0.f);
    if constexpr (__hip_internal::is_same<OT, bf16>::value)
        out[(size_t)n * 64 + lane] = __float2bfloat16(val);  // hb: re-read by gemm2, keep cached
    else
        __builtin_nontemporal_store(val, out + (size_t)n * 64 + lane);  // d_out: nt
}

extern "C" void kernel_launch(void* const* d_in, const int* in_sizes, int n_in,
                              void* d_out, int out_size, void* d_ws, size_t ws_size,
                              hipStream_t stream) {
    const float* x  = (const float*)d_in[0];
    const int*   ei = (const int*)d_in[1];
    const float* bq1 = (const float*)d_in[3];
    const float* bk1 = (const float*)d_in[5];
    const float* bv1 = (const float*)d_in[7];
    const float* bs1 = (const float*)d_in[9];
    const float* bq2 = (const float*)d_in[11];
    const float* bk2 = (const float*)d_in[13];
    const float* bv2 = (const float*)d_in[15];
    const float* bs2 = (const float*)d_in[17];

    WPtrs wp;
    wp.p[0] = (const float*)d_in[2];
    wp.p[1] = (const float*)d_in[4];
    wp.p[2] = (const float*)d_in[6];
    wp.p[3] = (const float*)d_in[8];
    wp.p[4] = (const float*)d_in[10];
    wp.p[5] = (const float*)d_in[12];
    wp.p[6] = (const float*)d_in[14];
    wp.p[7] = (const float*)d_in[16];

    const size_t N = N_NODES;
    bf16* xb  = (bf16*)d_ws;                 // NPAD*128
    bf16* hb  = xb + (size_t)NPAD * 128;     // NPAD*64
    bf16* qb  = hb + (size_t)NPAD * 64;      // N*64
    bf16* kvb = qb + N * 64;                 // 2*N*64 interleaved
    bf16* wb  = kvb + 2 * N * 64;            // 49152
    float* s  = (float*)(wb + 49152);        // N*64
    int* deg  = (int*)(s + N * 64);          // N
    int* off  = deg + N_NODES;               // N+1
    int* cur  = off + N_NODES + 1;           // N
    int* bsum = cur + N_NODES;               // NB_SCAN
    int* boff = bsum + NB_SCAN;              // NB_SCAN+1
    int* csr  = boff + NB_SCAN + 1;          // E

    const int aggGrid = (N_NODES * 64 + 255) / 256;

    // ---------------- prep + CSR ----------------
    hipMemsetAsync(deg, 0, N_NODES * sizeof(int), stream);
    prep<<<dim3(1024, 3), 256, 0, stream>>>(x, xb, wp, wb, ei, deg);
    scan1<<<NB_SCAN, 256, 0, stream>>>(deg, off, bsum);
    scan2<<<1, 256, 0, stream>>>(bsum, boff);
    scan3<<<NB_SCAN, 256, 0, stream>>>(off, boff, cur);

    // ---------------- Layer 1 (gemm + scatter fused) ----------------
    gemm1_scatter<<<GEMM_BLKS + SCAT_BLKS, 256, 0, stream>>>(
        xb, wb, bq1, bk1, bv1, bs1, qb, kvb, s, ei, cur, csr);
    agg_csr<4, true, bf16><<<aggGrid, 256, 0, stream>>>(off, csr, qb,
                                                        (const unsigned int*)kvb, s, hb);

    // ---------------- Layer 2 ----------------
    gemm2<<<GEMM_BLKS, 256, 0, stream>>>(hb, wb + 32768, bq2, bk2, bv2, bs2,
                                         qb, kvb, s);
    agg_csr<1, false, float><<<aggGrid, 256, 0, stream>>>(off, csr, qb,
                                                          (const unsigned int*)kvb, s,
                                                          (float*)d_out);
}

// Round 3
// 355.201 us; speedup vs baseline: 1.1170x; 1.1170x over previous
//
#include <hip/hip_runtime.h>
#include <hip/hip_bf16.h>

// ROUND 19. r18 FAILED (396.8, gemm1_scatter 100->140): edge batching reverted.
// Counter evidence: WRITE_SIZE 85.8 MB = 35 useful + ~51 MB amplification
// (800K x 64B line-granular random csr stores from all 8 XCDs). Dispatch is
// byte/transaction-bound at ~950 GB/s realized -> kill the amplification:
//   Pass A (fused with gemm1): bin edges by dst>>6 into 782 bucket windows,
//     packed (dst<<16)|src, cursor-bumped -> lines fill while L2-resident.
//   Pass B (new, 782 blocks): LDS-rank within bucket, dense stores into the
//     bucket's contiguous csr region.
// Predict: gemm1_scatter WRITE 85.8->~38 MB, dur 140->40-55 us; +passB ~10 us;
// total -> ~310-325. If gemm1_scatter stays >70 us: gemm writeback is floor.

#define N_NODES 50000
#define N_EDGES 800000
#define NB_SCAN 196   // ceil(50000/256)
#define NPAD    50048 // 782*64
#define GEMM_BLKS 782
#define SCAT_BLKS 3125 // 1 edge/thread
#define NBUCK 782      // ceil(50000/64) buckets of 64 nodes
#define CURSTRIDE 16   // one cursor per 64B line

using bf16 = __hip_bfloat16;
typedef __attribute__((ext_vector_type(8))) short bf16x8;
typedef __attribute__((ext_vector_type(4))) float f32x4;

__device__ __forceinline__ float b2f(unsigned short u) {
    unsigned int x = ((unsigned int)u) << 16;
    return __builtin_bit_cast(float, x);
}

struct WPtrs { const float* p[8]; };

// ---------------- fused prep: conv_x / conv_w / hist ----------------
__global__ __launch_bounds__(256) void prep(const float* __restrict__ x,
                                            bf16* __restrict__ xb,
                                            WPtrs wp, bf16* __restrict__ wb,
                                            const int* __restrict__ ei,
                                            int* __restrict__ deg) {
    const int gs = gridDim.x * 256;
    const int t0 = blockIdx.x * 256 + threadIdx.x;
    if (blockIdx.y == 0) {
        for (int i = t0; i < N_NODES * 128; i += gs)
            xb[i] = __float2bfloat16(x[i]);
    } else if (blockIdx.y == 1) {
        for (int i = t0; i < 49152; i += gs) {
            int y, o;
            if (i < 32768) { y = i >> 13; o = i & 8191; }
            else { y = 4 + ((i - 32768) >> 12); o = (i - 32768) & 4095; }
            wb[i] = __float2bfloat16(wp.p[y][o]);
        }
    } else {
        for (int e = t0; e < N_EDGES; e += gs)
            atomicAdd(&deg[ei[N_EDGES + e]], 1);
    }
}

// ---------------- MFMA GEMM body (64-row tile, 4 weight mats) ----------------
template <int K>
__device__ __forceinline__ void gemm_body(
    int blk, int tid,
    const bf16* __restrict__ A, const bf16* __restrict__ wb,
    const float* __restrict__ bq, const float* __restrict__ bk,
    const float* __restrict__ bv, const float* __restrict__ bs,
    bf16* __restrict__ qb, bf16* __restrict__ kvb, float* __restrict__ s) {
    const int wave = tid >> 6;
    const int lane = tid & 63;
    const int row0 = blk * 64;
    const int m  = lane & 15;
    const int kg = lane >> 4;
    const bf16* W = wb + (size_t)wave * 64 * K;

    f32x4 acc[4][4];
#pragma unroll
    for (int i = 0; i < 4; ++i)
#pragma unroll
        for (int j = 0; j < 4; ++j) acc[i][j] = (f32x4){0.f, 0.f, 0.f, 0.f};

#pragma unroll
    for (int k0 = 0; k0 < K; k0 += 32) {
        bf16x8 a[4], b[4];
#pragma unroll
        for (int i = 0; i < 4; ++i)
            a[i] = *(const bf16x8*)(A + (size_t)(row0 + i * 16 + m) * K + k0 + kg * 8);
#pragma unroll
        for (int j = 0; j < 4; ++j)
            b[j] = *(const bf16x8*)(W + (size_t)(j * 16 + m) * K + k0 + kg * 8);
#pragma unroll
        for (int i = 0; i < 4; ++i)
#pragma unroll
            for (int j = 0; j < 4; ++j)
                acc[i][j] = __builtin_amdgcn_mfma_f32_16x16x32_bf16(a[i], b[j], acc[i][j], 0, 0, 0);
    }

    const int crow = (lane >> 4) * 4;
    const int ccol = lane & 15;
    const float* B = (wave == 0) ? bq : (wave == 1) ? bk : (wave == 2) ? bv : bs;
    float bias[4];
#pragma unroll
    for (int j = 0; j < 4; ++j) bias[j] = B[j * 16 + ccol];

#pragma unroll
    for (int i = 0; i < 4; ++i)
#pragma unroll
        for (int r = 0; r < 4; ++r) {
            int gr = row0 + i * 16 + crow + r;
            if (gr >= N_NODES) continue;
#pragma unroll
            for (int j = 0; j < 4; ++j) {
                float val = acc[i][j][r] + bias[j];
                size_t idx = (size_t)gr * 64 + j * 16 + ccol;
                if (wave == 0) qb[idx] = __float2bfloat16(val);
                else if (wave == 1) kvb[idx * 2] = __float2bfloat16(val);
                else if (wave == 2) kvb[idx * 2 + 1] = __float2bfloat16(val);
                else s[idx] = val;
            }
        }
}

// layer-1 GEMM + pass-A binning fused (independent work in one dispatch).
// Pass A: 1 edge/thread. bucket = dst>>6 (782 windows). Packed (dst<<16)|src
// stored at pairs[off[bucket<<6] + cursor] -> dense line-filling stores.
__global__ __launch_bounds__(256) void gemm1_scatter(
    const bf16* __restrict__ A, const bf16* __restrict__ wb,
    const float* __restrict__ bq, const float* __restrict__ bk,
    const float* __restrict__ bv, const float* __restrict__ bs,
    bf16* __restrict__ qb, bf16* __restrict__ kvb, float* __restrict__ s,
    const int* __restrict__ ei, const int* __restrict__ off,
    int* __restrict__ bcur, unsigned int* __restrict__ pairs) {
    if (blockIdx.x < GEMM_BLKS) {
        gemm_body<128>(blockIdx.x, threadIdx.x, A, wb, bq, bk, bv, bs, qb, kvb, s);
    } else {
        int e = (blockIdx.x - GEMM_BLKS) * 256 + threadIdx.x;
        if (e < N_EDGES) {
            int d  = ei[N_EDGES + e];
            int sv = ei[e];
            int b  = d >> 6;
            int pos = atomicAdd(&bcur[b * CURSTRIDE], 1);
            pairs[off[b << 6] + pos] = ((unsigned int)d << 16) | (unsigned int)sv;
        }
    }
}

// Pass B: one block per bucket. Rank each dst via LDS counters; dense stores
// into the bucket's contiguous csr region [off[n0], off[nend]).
__global__ __launch_bounds__(256) void passB(const int* __restrict__ off,
                                             const unsigned int* __restrict__ pairs,
                                             int* __restrict__ csr) {
    __shared__ int lcnt[64];
    const int b = blockIdx.x;
    const int n0 = b << 6;
    const int nend = (n0 + 64 < N_NODES) ? n0 + 64 : N_NODES;
    if (threadIdx.x < 64) lcnt[threadIdx.x] = 0;
    const int p0 = off[n0];
    const int p1 = off[nend];
    __syncthreads();
    for (int j = p0 + threadIdx.x; j < p1; j += 256) {
        unsigned int pr = pairs[j];
        int d  = (int)(pr >> 16);
        int sv = (int)(pr & 0xffffu);
        int r = atomicAdd(&lcnt[d - n0], 1);
        csr[off[d] + r] = sv;
    }
}

__global__ __launch_bounds__(256) void gemm2(
    const bf16* __restrict__ A, const bf16* __restrict__ wb,
    const float* __restrict__ bq, const float* __restrict__ bk,
    const float* __restrict__ bv, const float* __restrict__ bs,
    bf16* __restrict__ qb, bf16* __restrict__ kvb, float* __restrict__ s) {
    gemm_body<64>(blockIdx.x, threadIdx.x, A, wb, bq, bk, bv, bs, qb, kvb, s);
}

// ---------------- CSR scan ----------------
__global__ __launch_bounds__(256) void scan1(const int* __restrict__ deg,
                                             int* __restrict__ off,
                                             int* __restrict__ bsum) {
    __shared__ int sm[256];
    int i = blockIdx.x * 256 + threadIdx.x;
    int v = (i < N_NODES) ? deg[i] : 0;
    sm[threadIdx.x] = v;
    __syncthreads();
    for (int st = 1; st < 256; st <<= 1) {
        int t = (threadIdx.x >= (unsigned)st) ? sm[threadIdx.x - st] : 0;
        __syncthreads();
        sm[threadIdx.x] += t;
        __syncthreads();
    }
    if (i < N_NODES) off[i] = sm[threadIdx.x] - v;
    if (threadIdx.x == 255) bsum[blockIdx.x] = sm[255];
}

__global__ __launch_bounds__(256) void scan2(const int* __restrict__ bsum,
                                             int* __restrict__ boff) {
    __shared__ int sm[256];
    int b = threadIdx.x;
    int v = (b < NB_SCAN) ? bsum[b] : 0;
    sm[b] = v;
    __syncthreads();
    for (int st = 1; st < 256; st <<= 1) {
        int t = (b >= st) ? sm[b - st] : 0;
        __syncthreads();
        sm[b] += t;
        __syncthreads();
    }
    if (b < NB_SCAN) boff[b] = sm[b] - v;
    if (b == 255) boff[NB_SCAN] = sm[255];
}

__global__ __launch_bounds__(256) void scan3(int* __restrict__ off,
                                             const int* __restrict__ boff,
                                             int* __restrict__ bcur) {
    int i = blockIdx.x * 256 + threadIdx.x;
    if (i < N_NODES) off[i] = off[i] + boff[blockIdx.x];
    if (i == 0) off[N_NODES] = boff[NB_SCAN];
    if (i < NBUCK * CURSTRIDE) bcur[i] = 0;
}

// ------------- Aggregation: wave/node, nt streaming, unroll 16 -------------
template <int H, bool RELU, typename OT>  // D = 64/H
__global__ __launch_bounds__(256) void agg_csr(const int* __restrict__ off,
                                               const int* __restrict__ csr_src,
                                               const bf16* __restrict__ qb,
                                               const unsigned int* __restrict__ kvu,
                                               const float* __restrict__ s,
                                               OT* __restrict__ out) {
    const int D = 64 / H;
    const float scale = (D == 16) ? 0.25f : 0.125f;
    const int lane = threadIdx.x & 63;
    const int n = (blockIdx.x * 256 + threadIdx.x) >> 6;
    if (n >= N_NODES) return;

    const float qv = b2f(__builtin_nontemporal_load(
        (const unsigned short*)qb + (size_t)n * 64 + lane));
    float acc = 0.f, dsum = 0.f;
    int j = off[n];
    const int j1 = off[n + 1];

    for (; j + 15 < j1; j += 16) {
        unsigned int w[16];
#pragma unroll
        for (int u = 0; u < 16; ++u)
            w[u] = kvu[(size_t)csr_src[j + u] * 64 + lane];
        float p[16];
#pragma unroll
        for (int u = 0; u < 16; ++u) p[u] = qv * b2f((unsigned short)w[u]);
#pragma unroll
        for (int o = 1; o < D; o <<= 1)
#pragma unroll
            for (int u = 0; u < 16; ++u) p[u] += __shfl_xor(p[u], o, 64);
#pragma unroll
        for (int u = 0; u < 16; ++u) {
            float e = __expf(p[u] * scale);
            acc += e * b2f((unsigned short)(w[u] >> 16));
            dsum += e;
        }
    }
    for (; j + 3 < j1; j += 4) {
        unsigned int w[4];
#pragma unroll
        for (int u = 0; u < 4; ++u)
            w[u] = kvu[(size_t)csr_src[j + u] * 64 + lane];
        float p[4];
#pragma unroll
        for (int u = 0; u < 4; ++u) p[u] = qv * b2f((unsigned short)w[u]);
#pragma unroll
        for (int o = 1; o < D; o <<= 1)
#pragma unroll
            for (int u = 0; u < 4; ++u) p[u] += __shfl_xor(p[u], o, 64);
#pragma unroll
        for (int u = 0; u < 4; ++u) {
            float e = __expf(p[u] * scale);
            acc += e * b2f((unsigned short)(w[u] >> 16));
            dsum += e;
        }
    }
    for (; j < j1; ++j) {
        unsigned int w = kvu[(size_t)csr_src[j] * 64 + lane];
        float p = qv * b2f((unsigned short)w);
#pragma unroll
        for (int o = 1; o < D; o <<= 1) p += __shfl_xor(p, o, 64);
        float e = __expf(p * scale);
        acc += e * b2f((unsigned short)(w >> 16));
        dsum += e;
    }
    float a = (dsum != 0.f) ? acc / dsum : 0.f;
    float sk = __builtin_nontemporal_load(s + (size_t)n * 64 + lane);
    float val = a + sk;
    if (RELU) val = fmaxf(val, 0.f);
    if constexpr (__hip_internal::is_same<OT, bf16>::value)
        out[(size_t)n * 64 + lane] = __float2bfloat16(val);  // hb: re-read by gemm2
    else
        __builtin_nontemporal_store(val, out + (size_t)n * 64 + lane);  // d_out: nt
}

extern "C" void kernel_launch(void* const* d_in, const int* in_sizes, int n_in,
                              void* d_out, int out_size, void* d_ws, size_t ws_size,
                              hipStream_t stream) {
    const float* x  = (const float*)d_in[0];
    const int*   ei = (const int*)d_in[1];
    const float* bq1 = (const float*)d_in[3];
    const float* bk1 = (const float*)d_in[5];
    const float* bv1 = (const float*)d_in[7];
    const float* bs1 = (const float*)d_in[9];
    const float* bq2 = (const float*)d_in[11];
    const float* bk2 = (const float*)d_in[13];
    const float* bv2 = (const float*)d_in[15];
    const float* bs2 = (const float*)d_in[17];

    WPtrs wp;
    wp.p[0] = (const float*)d_in[2];
    wp.p[1] = (const float*)d_in[4];
    wp.p[2] = (const float*)d_in[6];
    wp.p[3] = (const float*)d_in[8];
    wp.p[4] = (const float*)d_in[10];
    wp.p[5] = (const float*)d_in[12];
    wp.p[6] = (const float*)d_in[14];
    wp.p[7] = (const float*)d_in[16];

    const size_t N = N_NODES;
    bf16* xb  = (bf16*)d_ws;                 // NPAD*128
    bf16* hb  = xb + (size_t)NPAD * 128;     // NPAD*64
    bf16* qb  = hb + (size_t)NPAD * 64;      // N*64
    bf16* kvb = qb + N * 64;                 // 2*N*64 interleaved
    bf16* wb  = kvb + 2 * N * 64;            // 49152
    float* s  = (float*)(wb + 49152);        // N*64
    int* deg  = (int*)(s + N * 64);          // N
    int* off  = deg + N_NODES;               // N+1
    int* bcur = off + N_NODES + 1;           // NBUCK*CURSTRIDE (reuses old cur slot)
    int* bsum = bcur + N_NODES;              // NB_SCAN
    int* boff = bsum + NB_SCAN;              // NB_SCAN+1
    int* csr  = boff + NB_SCAN + 1;          // E
    unsigned int* pairs = (unsigned int*)(csr + N_EDGES); // E

    const int aggGrid = (N_NODES * 64 + 255) / 256;

    // ---------------- prep + CSR ----------------
    hipMemsetAsync(deg, 0, N_NODES * sizeof(int), stream);
    prep<<<dim3(1024, 3), 256, 0, stream>>>(x, xb, wp, wb, ei, deg);
    scan1<<<NB_SCAN, 256, 0, stream>>>(deg, off, bsum);
    scan2<<<1, 256, 0, stream>>>(bsum, boff);
    scan3<<<NB_SCAN, 256, 0, stream>>>(off, boff, bcur);

    // ---------------- Layer 1 (gemm + pass-A binning fused) ----------------
    gemm1_scatter<<<GEMM_BLKS + SCAT_BLKS, 256, 0, stream>>>(
        xb, wb, bq1, bk1, bv1, bs1, qb, kvb, s, ei, off, bcur, pairs);
    passB<<<NBUCK, 256, 0, stream>>>(off, pairs, csr);
    agg_csr<4, true, bf16><<<aggGrid, 256, 0, stream>>>(off, csr, qb,
                                                        (const unsigned int*)kvb, s, hb);

    // ---------------- Layer 2 ----------------
    gemm2<<<GEMM_BLKS, 256, 0, stream>>>(hb, wb + 32768, bq2, bk2, bv2, bs2,
                                         qb, kvb, s);
    agg_csr<1, false, float><<<aggGrid, 256, 0, stream>>>(off, csr, qb,
                                                          (const unsigned int*)kvb, s,
                                                          (float*)d_out);
}

// Round 4
// 330.981 us; speedup vs baseline: 1.1987x; 1.0732x over previous
//
#include <hip/hip_runtime.h>
#include <hip/hip_bf16.h>

// ROUND 20. r19 WIN (355.2, gemm1_scatter 74.5us) but WRITE_SIZE 72.3 MB vs
// 35 useful: ~37 MB amplification remains. Mechanism: pairs lines (16 slots)
// claimed by threads on different XCDs over dispatch lifetime -> partial-line
// writebacks from multiple non-coherent L2s. Fix: LDS multi-split binning.
//  Pass A (fused, 391 blks x 2048 edges): LDS hist over 196 buckets (dst>>8)
//    -> scan -> ONE global atomic per (block,bucket) (38K vs 800K) -> LDS
//    stage -> bucket-sorted copy-out (runs ~10 edges -> line-coalesced).
//  Pass B (196 blks): off-window in LDS, LDS-rank, dense csr stores.
// Predict: gemm1_scatter WRITE 72.3 -> ~38 MB, dur 74.5 -> 30-40us, total
// ~315us. If dur >=60 with WRITE ~38: gemm C-writeback is limiter -> next.

#define N_NODES 50000
#define N_EDGES 800000
#define NB_SCAN 196   // ceil(50000/256)
#define NPAD    50048 // 782*64
#define GEMM_BLKS 782
#define EPB 2048       // edges per scatter block
#define SCAT_BLKS 391  // ceil(800000/2048)
#define NBK 196        // buckets of 256 nodes (dst>>8)
#define CURSTRIDE 16   // one cursor per 64B line

using bf16 = __hip_bfloat16;
typedef __attribute__((ext_vector_type(8))) short bf16x8;
typedef __attribute__((ext_vector_type(4))) float f32x4;

__device__ __forceinline__ float b2f(unsigned short u) {
    unsigned int x = ((unsigned int)u) << 16;
    return __builtin_bit_cast(float, x);
}

struct WPtrs { const float* p[8]; };

// ---------------- fused prep: conv_x / conv_w / hist ----------------
__global__ __launch_bounds__(256) void prep(const float* __restrict__ x,
                                            bf16* __restrict__ xb,
                                            WPtrs wp, bf16* __restrict__ wb,
                                            const int* __restrict__ ei,
                                            int* __restrict__ deg) {
    const int gs = gridDim.x * 256;
    const int t0 = blockIdx.x * 256 + threadIdx.x;
    if (blockIdx.y == 0) {
        for (int i = t0; i < N_NODES * 128; i += gs)
            xb[i] = __float2bfloat16(x[i]);
    } else if (blockIdx.y == 1) {
        for (int i = t0; i < 49152; i += gs) {
            int y, o;
            if (i < 32768) { y = i >> 13; o = i & 8191; }
            else { y = 4 + ((i - 32768) >> 12); o = (i - 32768) & 4095; }
            wb[i] = __float2bfloat16(wp.p[y][o]);
        }
    } else {
        for (int e = t0; e < N_EDGES; e += gs)
            atomicAdd(&deg[ei[N_EDGES + e]], 1);
    }
}

// ---------------- MFMA GEMM body (64-row tile, 4 weight mats) ----------------
template <int K>
__device__ __forceinline__ void gemm_body(
    int blk, int tid,
    const bf16* __restrict__ A, const bf16* __restrict__ wb,
    const float* __restrict__ bq, const float* __restrict__ bk,
    const float* __restrict__ bv, const float* __restrict__ bs,
    bf16* __restrict__ qb, bf16* __restrict__ kvb, float* __restrict__ s) {
    const int wave = tid >> 6;
    const int lane = tid & 63;
    const int row0 = blk * 64;
    const int m  = lane & 15;
    const int kg = lane >> 4;
    const bf16* W = wb + (size_t)wave * 64 * K;

    f32x4 acc[4][4];
#pragma unroll
    for (int i = 0; i < 4; ++i)
#pragma unroll
        for (int j = 0; j < 4; ++j) acc[i][j] = (f32x4){0.f, 0.f, 0.f, 0.f};

#pragma unroll
    for (int k0 = 0; k0 < K; k0 += 32) {
        bf16x8 a[4], b[4];
#pragma unroll
        for (int i = 0; i < 4; ++i)
            a[i] = *(const bf16x8*)(A + (size_t)(row0 + i * 16 + m) * K + k0 + kg * 8);
#pragma unroll
        for (int j = 0; j < 4; ++j)
            b[j] = *(const bf16x8*)(W + (size_t)(j * 16 + m) * K + k0 + kg * 8);
#pragma unroll
        for (int i = 0; i < 4; ++i)
#pragma unroll
            for (int j = 0; j < 4; ++j)
                acc[i][j] = __builtin_amdgcn_mfma_f32_16x16x32_bf16(a[i], b[j], acc[i][j], 0, 0, 0);
    }

    const int crow = (lane >> 4) * 4;
    const int ccol = lane & 15;
    const float* B = (wave == 0) ? bq : (wave == 1) ? bk : (wave == 2) ? bv : bs;
    float bias[4];
#pragma unroll
    for (int j = 0; j < 4; ++j) bias[j] = B[j * 16 + ccol];

#pragma unroll
    for (int i = 0; i < 4; ++i)
#pragma unroll
        for (int r = 0; r < 4; ++r) {
            int gr = row0 + i * 16 + crow + r;
            if (gr >= N_NODES) continue;
#pragma unroll
            for (int j = 0; j < 4; ++j) {
                float val = acc[i][j][r] + bias[j];
                size_t idx = (size_t)gr * 64 + j * 16 + ccol;
                if (wave == 0) qb[idx] = __float2bfloat16(val);
                else if (wave == 1) kvb[idx * 2] = __float2bfloat16(val);
                else if (wave == 2) kvb[idx * 2 + 1] = __float2bfloat16(val);
                else s[idx] = val;
            }
        }
}

// layer-1 GEMM + pass-A LDS-binned scatter fused.
__global__ __launch_bounds__(256) void gemm1_scatter(
    const bf16* __restrict__ A, const bf16* __restrict__ wb,
    const float* __restrict__ bq, const float* __restrict__ bk,
    const float* __restrict__ bv, const float* __restrict__ bs,
    bf16* __restrict__ qb, bf16* __restrict__ kvb, float* __restrict__ s,
    const int* __restrict__ ei, const int* __restrict__ off,
    int* __restrict__ gcur, unsigned int* __restrict__ pairs) {
    __shared__ int hist[256];
    __shared__ int sm[256];
    __shared__ int obs[NBK];
    __shared__ unsigned int stage[EPB];

    if (blockIdx.x < GEMM_BLKS) {
        gemm_body<128>(blockIdx.x, threadIdx.x, A, wb, bq, bk, bv, bs, qb, kvb, s);
        return;
    }
    const int t = threadIdx.x;
    const int e0 = (blockIdx.x - GEMM_BLKS) * EPB;
    hist[t] = 0;
    __syncthreads();

    // per-edge: bucket + within-bucket rank via LDS atomics
    unsigned int pk[8];
    int bb[8], rr[8];
#pragma unroll
    for (int u = 0; u < 8; ++u) {
        const int e = e0 + u * 256 + t;
        if (e < N_EDGES) {
            int d  = ei[N_EDGES + e];
            int sv = ei[e];
            pk[u] = ((unsigned int)d << 16) | (unsigned int)sv;
            bb[u] = d >> 8;
            rr[u] = atomicAdd(&hist[bb[u]], 1);
        } else {
            bb[u] = -1;
        }
    }
    __syncthreads();

    // block-wide inclusive scan of hist (256 entries, Hillis-Steele)
    int hv = hist[t];
    sm[t] = hv;
    __syncthreads();
    for (int st = 1; st < 256; st <<= 1) {
        int tmp = (t >= st) ? sm[t - st] : 0;
        __syncthreads();
        sm[t] += tmp;
        __syncthreads();
    }
    const int total = sm[255];

    // one global reservation per non-empty bucket
    if (t < NBK && hv > 0) {
        int g = atomicAdd(&gcur[t * CURSTRIDE], hv);
        obs[t] = off[t << 8] + g - (sm[t] - hv);  // global base minus local run start
    }
    __syncthreads();

    // bin into LDS staging (bucket-sorted)
#pragma unroll
    for (int u = 0; u < 8; ++u)
        if (bb[u] >= 0) stage[(sm[bb[u]] - hist[bb[u]]) + rr[u]] = pk[u];
    __syncthreads();

    // copy-out: consecutive j within a bucket run -> contiguous global stores
    for (int j = t; j < total; j += 256) {
        unsigned int pr = stage[j];
        int b = pr >> 24;  // dst>>8
        pairs[obs[b] + j] = pr;
    }
}

// Pass B: one block per bucket (256 nodes). off-window in LDS, LDS-rank,
// dense stores into the bucket's contiguous csr region.
__global__ __launch_bounds__(256) void passB(const int* __restrict__ off,
                                             const unsigned int* __restrict__ pairs,
                                             int* __restrict__ csr) {
    __shared__ int lcnt[256];
    __shared__ int loff[256];
    const int b = blockIdx.x;
    const int n0 = b << 8;
    const int nend = (n0 + 256 < N_NODES) ? n0 + 256 : N_NODES;
    lcnt[threadIdx.x] = 0;
    if (n0 + threadIdx.x < nend) loff[threadIdx.x] = off[n0 + threadIdx.x];
    const int p0 = off[n0];
    const int p1 = off[nend];
    __syncthreads();
    for (int j = p0 + threadIdx.x; j < p1; j += 256) {
        unsigned int pr = pairs[j];
        int d  = (int)(pr >> 16);
        int sv = (int)(pr & 0xffffu);
        int r = atomicAdd(&lcnt[d - n0], 1);
        csr[loff[d - n0] + r] = sv;
    }
}

__global__ __launch_bounds__(256) void gemm2(
    const bf16* __restrict__ A, const bf16* __restrict__ wb,
    const float* __restrict__ bq, const float* __restrict__ bk,
    const float* __restrict__ bv, const float* __restrict__ bs,
    bf16* __restrict__ qb, bf16* __restrict__ kvb, float* __restrict__ s) {
    gemm_body<64>(blockIdx.x, threadIdx.x, A, wb, bq, bk, bv, bs, qb, kvb, s);
}

// ---------------- CSR scan ----------------
__global__ __launch_bounds__(256) void scan1(const int* __restrict__ deg,
                                             int* __restrict__ off,
                                             int* __restrict__ bsum) {
    __shared__ int sm[256];
    int i = blockIdx.x * 256 + threadIdx.x;
    int v = (i < N_NODES) ? deg[i] : 0;
    sm[threadIdx.x] = v;
    __syncthreads();
    for (int st = 1; st < 256; st <<= 1) {
        int t = (threadIdx.x >= (unsigned)st) ? sm[threadIdx.x - st] : 0;
        __syncthreads();
        sm[threadIdx.x] += t;
        __syncthreads();
    }
    if (i < N_NODES) off[i] = sm[threadIdx.x] - v;
    if (threadIdx.x == 255) bsum[blockIdx.x] = sm[255];
}

__global__ __launch_bounds__(256) void scan2(const int* __restrict__ bsum,
                                             int* __restrict__ boff) {
    __shared__ int sm[256];
    int b = threadIdx.x;
    int v = (b < NB_SCAN) ? bsum[b] : 0;
    sm[b] = v;
    __syncthreads();
    for (int st = 1; st < 256; st <<= 1) {
        int t = (b >= st) ? sm[b - st] : 0;
        __syncthreads();
        sm[b] += t;
        __syncthreads();
    }
    if (b < NB_SCAN) boff[b] = sm[b] - v;
    if (b == 255) boff[NB_SCAN] = sm[255];
}

__global__ __launch_bounds__(256) void scan3(int* __restrict__ off,
                                             const int* __restrict__ boff,
                                             int* __restrict__ gcur) {
    int i = blockIdx.x * 256 + threadIdx.x;
    if (i < N_NODES) off[i] = off[i] + boff[blockIdx.x];
    if (i == 0) off[N_NODES] = boff[NB_SCAN];
    if (i < NBK * CURSTRIDE) gcur[i] = 0;
}

// ------------- Aggregation: wave/node, nt streaming, unroll 16 -------------
template <int H, bool RELU, typename OT>  // D = 64/H
__global__ __launch_bounds__(256) void agg_csr(const int* __restrict__ off,
                                               const int* __restrict__ csr_src,
                                               const bf16* __restrict__ qb,
                                               const unsigned int* __restrict__ kvu,
                                               const float* __restrict__ s,
                                               OT* __restrict__ out) {
    const int D = 64 / H;
    const float scale = (D == 16) ? 0.25f : 0.125f;
    const int lane = threadIdx.x & 63;
    const int n = (blockIdx.x * 256 + threadIdx.x) >> 6;
    if (n >= N_NODES) return;

    const float qv = b2f(__builtin_nontemporal_load(
        (const unsigned short*)qb + (size_t)n * 64 + lane));
    float acc = 0.f, dsum = 0.f;
    int j = off[n];
    const int j1 = off[n + 1];

    for (; j + 15 < j1; j += 16) {
        unsigned int w[16];
#pragma unroll
        for (int u = 0; u < 16; ++u)
            w[u] = kvu[(size_t)csr_src[j + u] * 64 + lane];
        float p[16];
#pragma unroll
        for (int u = 0; u < 16; ++u) p[u] = qv * b2f((unsigned short)w[u]);
#pragma unroll
        for (int o = 1; o < D; o <<= 1)
#pragma unroll
            for (int u = 0; u < 16; ++u) p[u] += __shfl_xor(p[u], o, 64);
#pragma unroll
        for (int u = 0; u < 16; ++u) {
            float e = __expf(p[u] * scale);
            acc += e * b2f((unsigned short)(w[u] >> 16));
            dsum += e;
        }
    }
    for (; j + 3 < j1; j += 4) {
        unsigned int w[4];
#pragma unroll
        for (int u = 0; u < 4; ++u)
            w[u] = kvu[(size_t)csr_src[j + u] * 64 + lane];
        float p[4];
#pragma unroll
        for (int u = 0; u < 4; ++u) p[u] = qv * b2f((unsigned short)w[u]);
#pragma unroll
        for (int o = 1; o < D; o <<= 1)
#pragma unroll
            for (int u = 0; u < 4; ++u) p[u] += __shfl_xor(p[u], o, 64);
#pragma unroll
        for (int u = 0; u < 4; ++u) {
            float e = __expf(p[u] * scale);
            acc += e * b2f((unsigned short)(w[u] >> 16));
            dsum += e;
        }
    }
    for (; j < j1; ++j) {
        unsigned int w = kvu[(size_t)csr_src[j] * 64 + lane];
        float p = qv * b2f((unsigned short)w);
#pragma unroll
        for (int o = 1; o < D; o <<= 1) p += __shfl_xor(p, o, 64);
        float e = __expf(p * scale);
        acc += e * b2f((unsigned short)(w >> 16));
        dsum += e;
    }
    float a = (dsum != 0.f) ? acc / dsum : 0.f;
    float sk = __builtin_nontemporal_load(s + (size_t)n * 64 + lane);
    float val = a + sk;
    if (RELU) val = fmaxf(val, 0.f);
    if constexpr (__hip_internal::is_same<OT, bf16>::value)
        out[(size_t)n * 64 + lane] = __float2bfloat16(val);  // hb: re-read by gemm2
    else
        __builtin_nontemporal_store(val, out + (size_t)n * 64 + lane);  // d_out: nt
}

extern "C" void kernel_launch(void* const* d_in, const int* in_sizes, int n_in,
                              void* d_out, int out_size, void* d_ws, size_t ws_size,
                              hipStream_t stream) {
    const float* x  = (const float*)d_in[0];
    const int*   ei = (const int*)d_in[1];
    const float* bq1 = (const float*)d_in[3];
    const float* bk1 = (const float*)d_in[5];
    const float* bv1 = (const float*)d_in[7];
    const float* bs1 = (const float*)d_in[9];
    const float* bq2 = (const float*)d_in[11];
    const float* bk2 = (const float*)d_in[13];
    const float* bv2 = (const float*)d_in[15];
    const float* bs2 = (const float*)d_in[17];

    WPtrs wp;
    wp.p[0] = (const float*)d_in[2];
    wp.p[1] = (const float*)d_in[4];
    wp.p[2] = (const float*)d_in[6];
    wp.p[3] = (const float*)d_in[8];
    wp.p[4] = (const float*)d_in[10];
    wp.p[5] = (const float*)d_in[12];
    wp.p[6] = (const float*)d_in[14];
    wp.p[7] = (const float*)d_in[16];

    const size_t N = N_NODES;
    bf16* xb  = (bf16*)d_ws;                 // NPAD*128
    bf16* hb  = xb + (size_t)NPAD * 128;     // NPAD*64
    bf16* qb  = hb + (size_t)NPAD * 64;      // N*64
    bf16* kvb = qb + N * 64;                 // 2*N*64 interleaved
    bf16* wb  = kvb + 2 * N * 64;            // 49152
    float* s  = (float*)(wb + 49152);        // N*64
    int* deg  = (int*)(s + N * 64);          // N
    int* off  = deg + N_NODES;               // N+1
    int* gcur = off + N_NODES + 1;           // NBK*CURSTRIDE (in old cur slot, N ints)
    int* bsum = gcur + N_NODES;              // NB_SCAN
    int* boff = bsum + NB_SCAN;              // NB_SCAN+1
    int* csr  = boff + NB_SCAN + 1;          // E
    unsigned int* pairs = (unsigned int*)(csr + N_EDGES); // E

    const int aggGrid = (N_NODES * 64 + 255) / 256;

    // ---------------- prep + CSR ----------------
    hipMemsetAsync(deg, 0, N_NODES * sizeof(int), stream);
    prep<<<dim3(1024, 3), 256, 0, stream>>>(x, xb, wp, wb, ei, deg);
    scan1<<<NB_SCAN, 256, 0, stream>>>(deg, off, bsum);
    scan2<<<1, 256, 0, stream>>>(bsum, boff);
    scan3<<<NB_SCAN, 256, 0, stream>>>(off, boff, gcur);

    // ---------------- Layer 1 (gemm + pass-A binning fused) ----------------
    gemm1_scatter<<<GEMM_BLKS + SCAT_BLKS, 256, 0, stream>>>(
        xb, wb, bq1, bk1, bv1, bs1, qb, kvb, s, ei, off, gcur, pairs);
    passB<<<NBK, 256, 0, stream>>>(off, pairs, csr);
    agg_csr<4, true, bf16><<<aggGrid, 256, 0, stream>>>(off, csr, qb,
                                                        (const unsigned int*)kvb, s, hb);

    // ---------------- Layer 2 ----------------
    gemm2<<<GEMM_BLKS, 256, 0, stream>>>(hb, wb + 32768, bq2, bk2, bv2, bs2,
                                         qb, kvb, s);
    agg_csr<1, false, float><<<aggGrid, 256, 0, stream>>>(off, csr, qb,
                                                          (const unsigned int*)kvb, s,
                                                          (float*)d_out);
}